// Round 7
// baseline (615.091 us; speedup 1.0000x reference)
//
#include <hip/hip_runtime.h>
#include <hip/hip_bf16.h>

#define NB 8
#define NM 20000
#define NR 50000
#define NE 100000
#define BN_EPS 1e-5f

typedef unsigned int u32;

using short8 = __attribute__((ext_vector_type(8))) short;  // 8 bf16
using f32x4 = __attribute__((ext_vector_type(4))) float;

#define MFMA16(a, b, c) __builtin_amdgcn_mfma_f32_16x16x32_bf16(a, b, c, 0, 0, 0)

__device__ inline u32 f2bf_bits(float f) {
    u32 x = __float_as_uint(f);
    return (x + 0x7fffu + ((x >> 16) & 1u)) >> 16;
}
__device__ inline void storev(float* p, float v) { *p = v; }
__device__ inline void storev(__hip_bfloat16* p, float v) {
    *(unsigned short*)p = (unsigned short)f2bf_bits(v);
}

// accumulate 16 bf16 cols (32B) into fp32
__device__ inline void acc16(const __hip_bfloat16* p, float* g) {
    uint4 q0 = *(const uint4*)p;
    uint4 q1 = *(const uint4*)(p + 8);
    u32 ww[8] = {q0.x, q0.y, q0.z, q0.w, q1.x, q1.y, q1.z, q1.w};
#pragma unroll
    for (int q = 0; q < 8; ++q) {
        g[q * 2] += __uint_as_float(ww[q] << 16);
        g[q * 2 + 1] += __uint_as_float(ww[q] & 0xFFFF0000u);
    }
}

// ---------------------------------------------------------------------------
// CSR build (fused 4-list histogram / fill; scan unchanged)
// ---------------------------------------------------------------------------
__global__ __launch_bounds__(256) void hist4_k(const int* __restrict__ l0,
                                               const int* __restrict__ l1,
                                               const int* __restrict__ l2,
                                               const int* __restrict__ l3,
                                               int* c0, int* c1, int* c2, int* c3) {
    int i = blockIdx.x * 256 + threadIdx.x;
    if (i >= NE) return;
    const int* e;
    int* c;
    switch (blockIdx.y) {
        case 0: e = l0; c = c0; break;
        case 1: e = l1; c = c1; break;
        case 2: e = l2; c = c2; break;
        default: e = l3; c = c3; break;
    }
    atomicAdd(&c[e[NE + i]], 1);
}

__global__ __launch_bounds__(256) void fill4_k(
    const int* __restrict__ l0, const int* __restrict__ l1,
    const int* __restrict__ l2, const int* __restrict__ l3,
    const int* __restrict__ o0, const int* __restrict__ o1,
    const int* __restrict__ o2, const int* __restrict__ o3,
    int* u0, int* u1, int* u2, int* u3,
    int* x0, int* x1, int* x2, int* x3) {
    int i = blockIdx.x * 256 + threadIdx.x;
    if (i >= NE) return;
    const int *e, *o;
    int *cur, *idx;
    switch (blockIdx.y) {
        case 0: e = l0; o = o0; cur = u0; idx = x0; break;
        case 1: e = l1; o = o1; cur = u1; idx = x1; break;
        case 2: e = l2; o = o2; cur = u2; idx = x2; break;
        default: e = l3; o = o3; cur = u3; idx = x3; break;
    }
    int d = e[NE + i];
    int p = atomicAdd(&cur[d], 1);
    idx[o[d] + p] = e[i];
}

__global__ __launch_bounds__(1024) void scan4_k(
    const int* c0, int* o0, int n0, const int* c1, int* o1, int n1,
    const int* c2, int* o2, int n2, const int* c3, int* o3, int n3) {
    const int* c; int* o; int n;
    if (blockIdx.x == 0) { c = c0; o = o0; n = n0; }
    else if (blockIdx.x == 1) { c = c1; o = o1; n = n1; }
    else if (blockIdx.x == 2) { c = c2; o = o2; n = n2; }
    else { c = c3; o = o3; n = n3; }
    __shared__ int wsum[16];
    __shared__ int carry_s;
    int t = threadIdx.x, lane = t & 63, w = t >> 6;
    if (t == 0) carry_s = 0;
    __syncthreads();
    for (int base = 0; base < n; base += 1024) {
        int i = base + t;
        int x = (i < n) ? c[i] : 0;
#pragma unroll
        for (int s = 1; s < 64; s <<= 1) {
            int y = __shfl_up(x, s);
            if (lane >= s) x += y;
        }
        if (lane == 63) wsum[w] = x;
        __syncthreads();
        if (w == 0) {
            int ws = (lane < 16) ? wsum[lane] : 0;
#pragma unroll
            for (int s = 1; s < 16; s <<= 1) {
                int y = __shfl_up(ws, s);
                if (lane >= s) ws += y;
            }
            if (lane < 16) wsum[lane] = ws;
        }
        __syncthreads();
        int wbase = (w > 0) ? wsum[w - 1] : 0;
        int incl = x + wbase + carry_s;
        if (i < n) o[i + 1] = incl;
        __syncthreads();
        if (t == 1023) carry_s = incl;
        __syncthreads();
    }
    if (t == 0) o[0] = 0;
}

// ---------------------------------------------------------------------------
// nodes [B,M,128] f32 -> node-major bf16 [M,B,128]
// ---------------------------------------------------------------------------
__global__ __launch_bounds__(256) void cast_nodes_k(const float* __restrict__ in,
                                                    __hip_bfloat16* __restrict__ outp) {
    int id = blockIdx.x * 256 + threadIdx.x;
    int c8 = (id & 15) * 8;
    int b = (id >> 4) & 7;
    int m = id >> 7;
    const float* p = in + ((size_t)b * NM + m) * 128 + c8;
    float4 a = *(const float4*)p;
    float4 b2 = *(const float4*)(p + 4);
    u32 pk0 = f2bf_bits(a.x) | (f2bf_bits(a.y) << 16);
    u32 pk1 = f2bf_bits(a.z) | (f2bf_bits(a.w) << 16);
    u32 pk2 = f2bf_bits(b2.x) | (f2bf_bits(b2.y) << 16);
    u32 pk3 = f2bf_bits(b2.z) | (f2bf_bits(b2.w) << 16);
    *(uint4*)(outp + ((size_t)m * 8 + b) * 128 + c8) = make_uint4(pk0, pk1, pk2, pk3);
}

// ---------------------------------------------------------------------------
// deterministic stat reduction: part[nblk][256] -> pp[64][256]
// ---------------------------------------------------------------------------
__global__ __launch_bounds__(256) void reduce_part_k(const float* __restrict__ part,
                                                     int nblk, int chunk,
                                                     float* __restrict__ pp) {
    int t = threadIdx.x, j = blockIdx.x;
    int r0 = j * chunk;
    int r1 = min(nblk, r0 + chunk);
    float s = 0.f;
    for (int r = r0; r < r1; ++r) s += part[(size_t)r * 256 + t];
    pp[j * 256 + t] = s;
}

// ---------------------------------------------------------------------------
// prep1_frag: WtB1 = frag(bf16([w_ra1@w_rct ; w_ra1@w_prd] k-major));
// bias1 = [b_ra1 | w_ra1@b_rct | w_ra1@b_prd]
// ---------------------------------------------------------------------------
__global__ __launch_bounds__(128) void prep1_frag_k(
    const float* __restrict__ w_s1, const float* __restrict__ w_s2,
    const float* __restrict__ w_big, const float* __restrict__ b_s1,
    const float* __restrict__ b_s2, const float* __restrict__ b_big,
    short* __restrict__ WtB, float* __restrict__ bias) {
    int k = blockIdx.x;
    int h = threadIdx.x;
    __shared__ float col[128];
    const float* wsrc = (k < 128) ? w_s1 : w_s2;
    int kk = k & 127;
    col[h] = wsrc[h * 128 + kk];
    __syncthreads();
    float s = 0.f;
#pragma unroll 4
    for (int j = 0; j < 128; ++j) s = fmaf(w_big[h * 128 + j], col[j], s);
    int ks = k >> 5, hi = (k >> 3) & 3, j2 = k & 7;
    int ntile = h >> 4, lc = h & 15, lane = hi * 16 + lc;
    WtB[((ntile * 8 + ks) * 64 + lane) * 8 + j2] = (short)f2bf_bits(s);
    if (k == 0) {
        float sb1 = 0.f, sb2 = 0.f;
        for (int j = 0; j < 128; ++j) {
            sb1 = fmaf(w_big[h * 128 + j], b_s1[j], sb1);
            sb2 = fmaf(w_big[h * 128 + j], b_s2[j], sb2);
        }
        bias[h] = b_big[h];
        bias[128 + h] = sb1;
        bias[256 + h] = sb2;
    }
}

// ---------------------------------------------------------------------------
// mm2: two independent 128x128x128 products + matvecs
// C[h][d] = sum_j A[h][j]*B[j][d];  v[h] = sum_j A[h][j]*vin[j] (+vadd[h])
// ---------------------------------------------------------------------------
__global__ __launch_bounds__(128) void mm2_k(
    const float* __restrict__ A0, const float* __restrict__ B0,
    const float* __restrict__ vin0, const float* __restrict__ vadd0,
    float* __restrict__ C0, float* __restrict__ v0,
    const float* __restrict__ A1, const float* __restrict__ B1,
    const float* __restrict__ vin1, const float* __restrict__ vadd1,
    float* __restrict__ C1, float* __restrict__ v1) {
    int blk = blockIdx.x, d = threadIdx.x, h = blk & 127;
    bool sec = blk >= 128;
    const float* A = sec ? A1 : A0;
    const float* B = sec ? B1 : B0;
    const float* vin = sec ? vin1 : vin0;
    const float* vadd = sec ? vadd1 : vadd0;
    float* C = sec ? C1 : C0;
    float* v = sec ? v1 : v0;
    __shared__ float rowv[128];
    __shared__ float red[128];
    rowv[d] = A[h * 128 + d];
    __syncthreads();
    float s = 0.f;
#pragma unroll 4
    for (int j = 0; j < 128; ++j) s = fmaf(rowv[j], B[j * 128 + d], s);
    C[h * 128 + d] = s;
    red[d] = rowv[d] * vin[d];
    __syncthreads();
    for (int off = 64; off > 0; off >>= 1) {
        if (d < off) red[d] += red[d + off];
        __syncthreads();
    }
    if (d == 0) v[h] = red[0] + (vadd ? vadd[h] : 0.f);
}

// ---------------------------------------------------------------------------
// finalize1: from pp1 stats + precomputed Wq/c1, emit WtB2 frags + bias2.
// Wt2[k][h] = Wq_x[h][kk]*s1[kk]; bias2 = [b_ma1 | Wq_r@t1+c1_r | Wq_p@t1+c1_p]
// ---------------------------------------------------------------------------
__global__ __launch_bounds__(128) void finalize1_k(
    const float* __restrict__ pp, const float* __restrict__ Wq_r,
    const float* __restrict__ Wq_p, const float* __restrict__ c1_r,
    const float* __restrict__ c1_p, const float* __restrict__ b_ma1,
    const float* __restrict__ g, const float* __restrict__ beta, float Nf,
    short* __restrict__ WtB, float* __restrict__ bias) {
    int k = blockIdx.x, h = threadIdx.x, kk = k & 127;
    const float* Wq = (k < 128) ? Wq_r : Wq_p;
    float ssum = 0.f, ssq = 0.f;
#pragma unroll 8
    for (int j = 0; j < 64; ++j) {
        ssum += pp[j * 256 + kk];
        ssq += pp[j * 256 + 128 + kk];
    }
    float mean = ssum / Nf;
    float var = ssq / Nf - mean * mean;
    float sv = g[kk] * rsqrtf(var + BN_EPS);
    float v = Wq[h * 128 + kk] * sv;
    int ks = k >> 5, hi = (k >> 3) & 3, j2 = k & 7;
    int ntile = h >> 4, lc = h & 15, lane = hi * 16 + lc;
    WtB[((ntile * 8 + ks) * 64 + lane) * 8 + j2] = (short)f2bf_bits(v);
    if (kk == 0) {  // blocks 0 and 128 compute the bias vectors
        __shared__ float t1[128];
        float sh = 0.f, qh = 0.f;
#pragma unroll 8
        for (int j = 0; j < 64; ++j) {
            sh += pp[j * 256 + h];
            qh += pp[j * 256 + 128 + h];
        }
        float mh = sh / Nf;
        float vh = qh / Nf - mh * mh;
        float svh = g[h] * rsqrtf(vh + BN_EPS);
        t1[h] = beta[h] - mh * svh;
        __syncthreads();
        float sb = 0.f;
#pragma unroll 4
        for (int d = 0; d < 128; ++d) sb = fmaf(Wq[h * 128 + d], t1[d], sb);
        if (k == 0) {
            bias[h] = b_ma1[h];
            bias[128 + h] = sb + c1_r[h];
        } else {
            bias[256 + h] = sb + c1_p[h];
        }
    }
}

// ---------------------------------------------------------------------------
// finalize2: from pp2 stats, emit WtBo frags (K=128) + b_out.
// WtBo[k][h] = w_ma2[h][k]*s2[k]; b_out = w_ma2@t2 + b_ma2
// ---------------------------------------------------------------------------
__global__ __launch_bounds__(128) void finalize2_k(
    const float* __restrict__ pp, const float* __restrict__ w_ma2,
    const float* __restrict__ b_ma2, const float* __restrict__ g,
    const float* __restrict__ beta, float Nf, short* __restrict__ WtBo,
    float* __restrict__ b_out) {
    int k = blockIdx.x, h = threadIdx.x;
    float ssum = 0.f, ssq = 0.f;
#pragma unroll 8
    for (int j = 0; j < 64; ++j) {
        ssum += pp[j * 256 + k];
        ssq += pp[j * 256 + 128 + k];
    }
    float mean = ssum / Nf;
    float var = ssq / Nf - mean * mean;
    float sv = g[k] * rsqrtf(var + BN_EPS);
    float v = w_ma2[h * 128 + k] * sv;
    int ks = k >> 5, hi = (k >> 3) & 3, j2 = k & 7;
    int ntile = h >> 4, lc = h & 15, lane = hi * 16 + lc;
    WtBo[((ntile * 4 + ks) * 64 + lane) * 8 + j2] = (short)f2bf_bits(v);
    if (k == 0) {
        __shared__ float t2[128];
        float sh = 0.f, qh = 0.f;
#pragma unroll 8
        for (int j = 0; j < 64; ++j) {
            sh += pp[j * 256 + h];
            qh += pp[j * 256 + 128 + h];
        }
        float mh = sh / Nf;
        float vh = qh / Nf - mh * mh;
        float svh = g[h] * rsqrtf(vh + BN_EPS);
        t2[h] = beta[h] - mh * svh;
        __syncthreads();
        float sb = 0.f;
#pragma unroll 4
        for (int d = 0; d < 128; ++d) sb = fmaf(w_ma2[h * 128 + d], t2[d], sb);
        b_out[h] = sb + b_ma2[h];
    }
}

// ---------------------------------------------------------------------------
// dense MFMA GEMM (GEMM5): Out[n,0:128] = bf16(A[n,0:128]) @ W + bias
// In-place safe (A fully staged to LDS before stores).
// ---------------------------------------------------------------------------
__global__ __launch_bounds__(512, 4) void gemm_dense_mfma(
    const float* A, const short* __restrict__ WtB,
    const float* __restrict__ biasv, float* Out) {
    __shared__ alignas(16) short Asm[64][136];
    const int t = threadIdx.x, n0 = blockIdx.x * 64;
    const int lane = t & 63, w = t >> 6;
    const int lrow = lane & 15, lhi = lane >> 4;

    {
        int row = t >> 3, g8 = t & 7;
        const float* p = A + (size_t)(n0 + row) * 128 + g8 * 16;
        u32* aw = (u32*)&Asm[0][0];
        int wb = row * 68 + g8 * 8;
#pragma unroll
        for (int c = 0; c < 2; ++c) {
            float4 a = *(const float4*)(p + c * 8);
            float4 b2 = *(const float4*)(p + c * 8 + 4);
            u32 pk0 = f2bf_bits(a.x) | (f2bf_bits(a.y) << 16);
            u32 pk1 = f2bf_bits(a.z) | (f2bf_bits(a.w) << 16);
            u32 pk2 = f2bf_bits(b2.x) | (f2bf_bits(b2.y) << 16);
            u32 pk3 = f2bf_bits(b2.z) | (f2bf_bits(b2.w) << 16);
            *(uint4*)&aw[wb + c * 4] = make_uint4(pk0, pk1, pk2, pk3);
        }
    }
    short8 bfrag[4];
#pragma unroll
    for (int ks = 0; ks < 4; ++ks)
        bfrag[ks] = *(const short8*)(WtB + (size_t)((w * 4 + ks) * 64 + lane) * 8);
    __syncthreads();

    f32x4 acc[4];
#pragma unroll
    for (int rt = 0; rt < 4; ++rt) acc[rt] = (f32x4){0.f, 0.f, 0.f, 0.f};
#pragma unroll
    for (int rt = 0; rt < 4; ++rt)
#pragma unroll
        for (int ks = 0; ks < 4; ++ks) {
            short8 af = *(const short8*)&Asm[rt * 16 + lrow][ks * 32 + lhi * 8];
            acc[rt] = MFMA16(af, bfrag[ks], acc[rt]);
        }
    int col = w * 16 + lrow;
    float bb = biasv[col];
#pragma unroll
    for (int rt = 0; rt < 4; ++rt)
#pragma unroll
        for (int i = 0; i < 4; ++i) {
            int row = rt * 16 + lhi * 4 + i;
            Out[(size_t)(n0 + row) * 128 + col] = acc[rt][i] + bb;
        }
}

// ---------------------------------------------------------------------------
// MFMA gather GEMM v3: node-major src [nsrc, B=8, 128] bf16.
// Block = 4 bins x 8 batches = 32 rows, 512 threads = 8 waves.
// Wave w owns (bin = bin0 + (w>>1), half = w&1): its own edge list (avg ~2
// edges serial). lane: batch = lane>>3, ck = lane&7; one 2KB burst per edge.
// Halves write disjoint K-ranges of A (no merge). Then 32x128 MFMA: wave w ->
// col-tile w, row-tiles 0..1. Per-block BN partials -> part[blk][256].
// PERM: write Out row (batch*permN + bin) (un-permute to batch-major).
// ---------------------------------------------------------------------------
template <typename OT, bool PERM>
__global__ __launch_bounds__(512, 8) void gemm_gather_mfma(
    const __hip_bfloat16* __restrict__ src,
    const int* __restrict__ off1, const int* __restrict__ idx1,
    const int* __restrict__ off2, const int* __restrict__ idx2,
    const short* __restrict__ WtB, const float* __restrict__ biasv,
    OT* __restrict__ Out, int permN, float* __restrict__ part) {
    __shared__ alignas(16) short Asm[32][264];
    __shared__ float m1s[32], m2s[32];
    const int t = threadIdx.x;
    const int lane = t & 63;
    const int w = __builtin_amdgcn_readfirstlane(t >> 6);
    const int lrow = lane & 15, lhi = lane >> 4;
    const int bin0 = blockIdx.x * 4;

    // B fragments early (in flight during gather); wave w -> col-tile w
    short8 bfrag[8];
#pragma unroll
    for (int ks = 0; ks < 8; ++ks)
        bfrag[ks] = *(const short8*)(WtB + (size_t)((w * 8 + ks) * 64 + lane) * 8);

    // ---- gather: wave w -> (bin w>>1, half w&1) ----
    {
        const int bin_ib = w >> 1, half = w & 1;
        const int rb = bin0 + bin_ib;
        const int batch = lane >> 3, ck = lane & 7;
        const int arow = bin_ib * 8 + batch;
        const __hip_bfloat16* lsrc = src + batch * 128 + ck * 16;
        const int* offp = half ? off2 : off1;
        const int* idxp = half ? idx2 : idx1;
        int e0 = offp[rb], e1 = offp[rb + 1];
        float g[16];
#pragma unroll
        for (int j = 0; j < 16; ++j) g[j] = 0.f;
        int e = e0;
        for (; e + 2 <= e1; e += 2) {
            int i0 = idxp[e], i1 = idxp[e + 1];
            acc16(lsrc + (size_t)i0 * 1024, g);
            acc16(lsrc + (size_t)i1 * 1024, g);
        }
        if (e < e1) acc16(lsrc + (size_t)idxp[e] * 1024, g);
        int cnt = e1 - e0;
        float sc = (cnt > 0) ? 1.f / (float)cnt : 0.f;
        if (ck == 0) (half ? m2s : m1s)[arow] = (cnt > 0) ? 1.f : 0.f;
        u32* aw = (u32*)&Asm[0][0];
        int wb = arow * 132 + half * 64 + ck * 8;
        u32 pk[8];
#pragma unroll
        for (int q = 0; q < 8; ++q)
            pk[q] = f2bf_bits(g[q * 2] * sc) | (f2bf_bits(g[q * 2 + 1] * sc) << 16);
        *(uint4*)&aw[wb] = make_uint4(pk[0], pk[1], pk[2], pk[3]);
        *(uint4*)&aw[wb + 4] = make_uint4(pk[4], pk[5], pk[6], pk[7]);
    }
    __syncthreads();

    // ---- MFMA: 2 row-tiles x 8 k-steps; wave w -> col-tile w ----
    f32x4 acc[2];
#pragma unroll
    for (int rt = 0; rt < 2; ++rt) acc[rt] = (f32x4){0.f, 0.f, 0.f, 0.f};
#pragma unroll
    for (int rt = 0; rt < 2; ++rt)
#pragma unroll
        for (int ks = 0; ks < 8; ++ks) {
            short8 af = *(const short8*)&Asm[rt * 16 + lrow][ks * 32 + lhi * 8];
            acc[rt] = MFMA16(af, bfrag[ks], acc[rt]);
        }

    // ---- epilogue ----
    const int col = w * 16 + lrow;
    float bb = biasv[col], bm1 = biasv[128 + col], bm2 = biasv[256 + col];
    float ps = 0.f, pq = 0.f;
#pragma unroll
    for (int rt = 0; rt < 2; ++rt)
#pragma unroll
        for (int i = 0; i < 4; ++i) {
            int row = rt * 16 + lhi * 4 + i;
            float v = acc[rt][i] + bb + m1s[row] * bm1 + m2s[row] * bm2;
            v = fmaxf(v, 0.f);
            ps += v;
            pq += v * v;
            size_t orow = PERM ? ((size_t)(row & 7) * permN + (bin0 + (row >> 3)))
                               : (size_t)(blockIdx.x * 32 + row);
            storev(&Out[orow * 128 + col], v);
        }
    ps += __shfl_xor(ps, 16);
    ps += __shfl_xor(ps, 32);
    pq += __shfl_xor(pq, 16);
    pq += __shfl_xor(pq, 32);
    if (lhi == 0) {
        part[(size_t)blockIdx.x * 256 + col] = ps;
        part[(size_t)blockIdx.x * 256 + 128 + col] = pq;
    }
}

// ---------------------------------------------------------------------------
// launch
// ---------------------------------------------------------------------------
extern "C" void kernel_launch(void* const* d_in, const int* in_sizes, int n_in,
                              void* d_out, int out_size, void* d_ws, size_t ws_size,
                              hipStream_t stream) {
    const float* nodes = (const float*)d_in[0];
    const int* r2e = (const int*)d_in[1];
    const int* p2e = (const int*)d_in[2];
    const int* e2r = (const int*)d_in[3];
    const int* e2p = (const int*)d_in[4];
    const float* w_rct = (const float*)d_in[5];
    const float* b_rct = (const float*)d_in[6];
    const float* w_prd = (const float*)d_in[7];
    const float* b_prd = (const float*)d_in[8];
    const float* w_ra1 = (const float*)d_in[9];
    const float* b_ra1 = (const float*)d_in[10];
    const float* bn_r_g = (const float*)d_in[11];
    const float* bn_r_b = (const float*)d_in[12];
    const float* w_ra2 = (const float*)d_in[13];
    const float* b_ra2 = (const float*)d_in[14];
    const float* w_r2rct = (const float*)d_in[15];
    const float* b_r2rct = (const float*)d_in[16];
    const float* w_r2prd = (const float*)d_in[17];
    const float* b_r2prd = (const float*)d_in[18];
    const float* w_ma1 = (const float*)d_in[19];
    const float* b_ma1 = (const float*)d_in[20];
    const float* bn_m_g = (const float*)d_in[21];
    const float* bn_m_b = (const float*)d_in[22];
    const float* w_ma2 = (const float*)d_in[23];
    const float* b_ma2 = (const float*)d_in[24];

    char* ws = (char*)d_ws;
    size_t off = 0;
    auto alloc = [&](size_t bytes) -> char* {
        off = (off + 255) & ~(size_t)255;
        char* p = ws + off;
        off += bytes;
        return p;
    };

    const size_t H1B = (size_t)NR * NB * 128 * 2;  // 102.4 MB node-major [R,B,128]
    __hip_bfloat16* h1 = (__hip_bfloat16*)alloc(H1B);

    char* cntcur = alloc((size_t)8 * (NR + NR + NM + NM));
    int* cnt_r = (int*)cntcur;
    int* cnt_p = cnt_r + NR;
    int* cnt_er = cnt_p + NR;
    int* cnt_ep = cnt_er + NM;
    int* cur_r = cnt_ep + NM;
    int* cur_p = cur_r + NR;
    int* cur_er = cur_p + NR;
    int* cur_ep = cur_er + NM;
    int* off_r = (int*)alloc((NR + 1) * 4);
    int* off_p = (int*)alloc((NR + 1) * 4);
    int* off_er = (int*)alloc((NM + 1) * 4);
    int* off_ep = (int*)alloc((NM + 1) * 4);
    int* idx_r = (int*)alloc(NE * 4);
    int* idx_p = (int*)alloc(NE * 4);
    int* idx_er = (int*)alloc(NE * 4);
    int* idx_ep = (int*)alloc(NE * 4);

    float* bias1 = (float*)alloc(3 * 128 * 4);
    float* bias2 = (float*)alloc(3 * 128 * 4);
    float* b_out = (float*)alloc(128 * 4);
    float* P_r = (float*)alloc(128 * 128 * 4);
    float* P_p = (float*)alloc(128 * 128 * 4);
    float* Wq_r = (float*)alloc(128 * 128 * 4);
    float* Wq_p = (float*)alloc(128 * 128 * 4);
    float* c1a_r = (float*)alloc(128 * 4);
    float* c1a_p = (float*)alloc(128 * 4);
    float* c1_r = (float*)alloc(128 * 4);
    float* c1_p = (float*)alloc(128 * 4);
    short* WtB1 = (short*)alloc(256 * 128 * 2);
    short* WtB2 = (short*)alloc(256 * 128 * 2);
    short* WtBo = (short*)alloc(128 * 128 * 2);
    const int NBLK1 = NR / 4;  // 12500
    const int NBLK2 = NM / 4;  // 5000
    float* part1 = (float*)alloc((size_t)NBLK1 * 256 * 4);  // 12.8 MB
    float* part2 = part1;                                   // sequential reuse
    float* pp1 = (float*)alloc(64 * 256 * 4);
    float* pp2 = pp1;  // sequential reuse
    (void)ws_size;

    // nb16 [M,B,128] bf16 (41 MB) lives in d_out; later overwritten by h2
    __hip_bfloat16* nb16 = (__hip_bfloat16*)d_out;
    float* h2 = (float*)d_out;

    hipMemsetAsync(cntcur, 0, (size_t)8 * (NR + NR + NM + NM), stream);

    // ---- CSR build (fused) ----
    const int EB = (NE + 255) / 256;
    hist4_k<<<dim3(EB, 4), 256, 0, stream>>>(r2e, p2e, e2r, e2p,
                                             cnt_r, cnt_p, cnt_er, cnt_ep);
    scan4_k<<<4, 1024, 0, stream>>>(cnt_r, off_r, NR, cnt_p, off_p, NR,
                                    cnt_er, off_er, NM, cnt_ep, off_ep, NM);
    fill4_k<<<dim3(EB, 4), 256, 0, stream>>>(r2e, p2e, e2r, e2p,
                                             off_r, off_p, off_er, off_ep,
                                             cur_r, cur_p, cur_er, cur_ep,
                                             idx_r, idx_p, idx_er, idx_ep);

    // ---- cast nodes -> node-major bf16 ----
    cast_nodes_k<<<(NB * NM * 128 / 8) / 256, 256, 0, stream>>>(nodes, nb16);

    // ---- stage-1 weights (direct to fragments) + stat-independent products ----
    prep1_frag_k<<<256, 128, 0, stream>>>(w_rct, w_prd, w_ra1, b_rct, b_prd, b_ra1,
                                          WtB1, bias1);
    // P_x = w_ma1 @ w_r2x ; c1a_x = w_ma1 @ b_r2x
    mm2_k<<<256, 128, 0, stream>>>(w_ma1, w_r2rct, b_r2rct, nullptr, P_r, c1a_r,
                                   w_ma1, w_r2prd, b_r2prd, nullptr, P_p, c1a_p);
    // Wq_x = P_x @ w_ra2 ; c1_x = P_x @ b_ra2 + c1a_x
    mm2_k<<<256, 128, 0, stream>>>(P_r, w_ra2, b_ra2, c1a_r, Wq_r, c1_r,
                                   P_p, w_ra2, b_ra2, c1a_p, Wq_p, c1_p);

    // ---- GEMM2 (gather): h1 = relu(gather(nb16)@Wt1 + biases) + BN1 partials ----
    gemm_gather_mfma<__hip_bfloat16, false><<<NBLK1, 512, 0, stream>>>(
        nb16, off_r, idx_r, off_p, idx_p, WtB1, bias1, h1, 0, part1);
    reduce_part_k<<<64, 256, 0, stream>>>(part1, NBLK1, (NBLK1 + 63) / 64, pp1);
    finalize1_k<<<256, 128, 0, stream>>>(pp1, Wq_r, Wq_p, c1_r, c1_p, b_ma1,
                                         bn_r_g, bn_r_b, (float)((size_t)NB * NR),
                                         WtB2, bias2);

    // ---- GEMM4 (gather): h2[b,m,:] = relu(gather(h1)@Wt2 + biases) -> d_out ----
    gemm_gather_mfma<float, true><<<NBLK2, 512, 0, stream>>>(
        h1, off_er, idx_er, off_ep, idx_ep, WtB2, bias2, h2, NM, part2);
    reduce_part_k<<<64, 256, 0, stream>>>(part2, NBLK2, (NBLK2 + 63) / 64, pp2);
    finalize2_k<<<128, 128, 0, stream>>>(pp2, w_ma2, b_ma2, bn_m_g, bn_m_b,
                                         (float)((size_t)NB * NM), WtBo, b_out);

    // ---- GEMM5 (MFMA) in-place on d_out ----
    gemm_dense_mfma<<<(NB * NM) / 64, 512, 0, stream>>>(h2, WtBo, b_out, (float*)d_out);
}

// Round 8
// 403.694 us; speedup vs baseline: 1.5237x; 1.5237x over previous
//
#include <hip/hip_runtime.h>
#include <hip/hip_bf16.h>

#define NB 8
#define NM 20000
#define NR 50000
#define NE 100000
#define BN_EPS 1e-5f

typedef unsigned int u32;

using short8 = __attribute__((ext_vector_type(8))) short;  // 8 bf16
using f32x4 = __attribute__((ext_vector_type(4))) float;

#define MFMA16(a, b, c) __builtin_amdgcn_mfma_f32_16x16x32_bf16(a, b, c, 0, 0, 0)

__device__ inline u32 f2bf_bits(float f) {
    u32 x = __float_as_uint(f);
    return (x + 0x7fffu + ((x >> 16) & 1u)) >> 16;
}
__device__ inline void storev(float* p, float v) { *p = v; }
__device__ inline void storev(__hip_bfloat16* p, float v) {
    *(unsigned short*)p = (unsigned short)f2bf_bits(v);
}

// accumulate 16 bf16 cols (32B) into fp32
__device__ inline void acc16(const __hip_bfloat16* p, float* g) {
    uint4 q0 = *(const uint4*)p;
    uint4 q1 = *(const uint4*)(p + 8);
    u32 ww[8] = {q0.x, q0.y, q0.z, q0.w, q1.x, q1.y, q1.z, q1.w};
#pragma unroll
    for (int q = 0; q < 8; ++q) {
        g[q * 2] += __uint_as_float(ww[q] << 16);
        g[q * 2 + 1] += __uint_as_float(ww[q] & 0xFFFF0000u);
    }
}

// ---------------------------------------------------------------------------
// CSR build (fused 4-list histogram / fill)
// ---------------------------------------------------------------------------
__global__ __launch_bounds__(256) void hist4_k(const int* __restrict__ l0,
                                               const int* __restrict__ l1,
                                               const int* __restrict__ l2,
                                               const int* __restrict__ l3,
                                               int* c0, int* c1, int* c2, int* c3) {
    int i = blockIdx.x * 256 + threadIdx.x;
    if (i >= NE) return;
    const int* e;
    int* c;
    switch (blockIdx.y) {
        case 0: e = l0; c = c0; break;
        case 1: e = l1; c = c1; break;
        case 2: e = l2; c = c2; break;
        default: e = l3; c = c3; break;
    }
    atomicAdd(&c[e[NE + i]], 1);
}

__global__ __launch_bounds__(256) void fill4_k(
    const int* __restrict__ l0, const int* __restrict__ l1,
    const int* __restrict__ l2, const int* __restrict__ l3,
    const int* __restrict__ o0, const int* __restrict__ o1,
    const int* __restrict__ o2, const int* __restrict__ o3,
    int* u0, int* u1, int* u2, int* u3,
    int* x0, int* x1, int* x2, int* x3) {
    int i = blockIdx.x * 256 + threadIdx.x;
    if (i >= NE) return;
    const int *e, *o;
    int *cur, *idx;
    switch (blockIdx.y) {
        case 0: e = l0; o = o0; cur = u0; idx = x0; break;
        case 1: e = l1; o = o1; cur = u1; idx = x1; break;
        case 2: e = l2; o = o2; cur = u2; idx = x2; break;
        default: e = l3; o = o3; cur = u3; idx = x3; break;
    }
    int d = e[NE + i];
    int p = atomicAdd(&cur[d], 1);
    idx[o[d] + p] = e[i];
}

__global__ __launch_bounds__(1024) void scan4_k(
    const int* c0, int* o0, int n0, const int* c1, int* o1, int n1,
    const int* c2, int* o2, int n2, const int* c3, int* o3, int n3) {
    const int* c; int* o; int n;
    if (blockIdx.x == 0) { c = c0; o = o0; n = n0; }
    else if (blockIdx.x == 1) { c = c1; o = o1; n = n1; }
    else if (blockIdx.x == 2) { c = c2; o = o2; n = n2; }
    else { c = c3; o = o3; n = n3; }
    __shared__ int wsum[16];
    __shared__ int carry_s;
    int t = threadIdx.x, lane = t & 63, w = t >> 6;
    if (t == 0) carry_s = 0;
    __syncthreads();
    for (int base = 0; base < n; base += 1024) {
        int i = base + t;
        int x = (i < n) ? c[i] : 0;
#pragma unroll
        for (int s = 1; s < 64; s <<= 1) {
            int y = __shfl_up(x, s);
            if (lane >= s) x += y;
        }
        if (lane == 63) wsum[w] = x;
        __syncthreads();
        if (w == 0) {
            int ws = (lane < 16) ? wsum[lane] : 0;
#pragma unroll
            for (int s = 1; s < 16; s <<= 1) {
                int y = __shfl_up(ws, s);
                if (lane >= s) ws += y;
            }
            if (lane < 16) wsum[lane] = ws;
        }
        __syncthreads();
        int wbase = (w > 0) ? wsum[w - 1] : 0;
        int incl = x + wbase + carry_s;
        if (i < n) o[i + 1] = incl;
        __syncthreads();
        if (t == 1023) carry_s = incl;
        __syncthreads();
    }
    if (t == 0) o[0] = 0;
}

// ---------------------------------------------------------------------------
// nodes [B,M,128] f32 -> node-major bf16 [M,B,128]
// ---------------------------------------------------------------------------
__global__ __launch_bounds__(256) void cast_nodes_k(const float* __restrict__ in,
                                                    __hip_bfloat16* __restrict__ outp) {
    int id = blockIdx.x * 256 + threadIdx.x;
    int c8 = (id & 15) * 8;
    int b = (id >> 4) & 7;
    int m = id >> 7;
    const float* p = in + ((size_t)b * NM + m) * 128 + c8;
    float4 a = *(const float4*)p;
    float4 b2 = *(const float4*)(p + 4);
    u32 pk0 = f2bf_bits(a.x) | (f2bf_bits(a.y) << 16);
    u32 pk1 = f2bf_bits(a.z) | (f2bf_bits(a.w) << 16);
    u32 pk2 = f2bf_bits(b2.x) | (f2bf_bits(b2.y) << 16);
    u32 pk3 = f2bf_bits(b2.z) | (f2bf_bits(b2.w) << 16);
    *(uint4*)(outp + ((size_t)m * 8 + b) * 128 + c8) = make_uint4(pk0, pk1, pk2, pk3);
}

// ---------------------------------------------------------------------------
// deterministic stat reduction: part[nblk][256] -> pp[64][256]
// ---------------------------------------------------------------------------
__global__ __launch_bounds__(256) void reduce_part_k(const float* __restrict__ part,
                                                     int nblk, int chunk,
                                                     float* __restrict__ pp) {
    int t = threadIdx.x, j = blockIdx.x;
    int r0 = j * chunk;
    int r1 = min(nblk, r0 + chunk);
    float s = 0.f;
    for (int r = r0; r < r1; ++r) s += part[(size_t)r * 256 + t];
    pp[j * 256 + t] = s;
}

// ---------------------------------------------------------------------------
// prep1_frag: WtB1 = frag(bf16([w_ra1@w_rct ; w_ra1@w_prd] k-major));
// bias1 = [b_ra1 | w_ra1@b_rct | w_ra1@b_prd]
// ---------------------------------------------------------------------------
__global__ __launch_bounds__(128) void prep1_frag_k(
    const float* __restrict__ w_s1, const float* __restrict__ w_s2,
    const float* __restrict__ w_big, const float* __restrict__ b_s1,
    const float* __restrict__ b_s2, const float* __restrict__ b_big,
    short* __restrict__ WtB, float* __restrict__ bias) {
    int k = blockIdx.x;
    int h = threadIdx.x;
    __shared__ float col[128];
    const float* wsrc = (k < 128) ? w_s1 : w_s2;
    int kk = k & 127;
    col[h] = wsrc[h * 128 + kk];
    __syncthreads();
    float s = 0.f;
#pragma unroll 4
    for (int j = 0; j < 128; ++j) s = fmaf(w_big[h * 128 + j], col[j], s);
    int ks = k >> 5, hi = (k >> 3) & 3, j2 = k & 7;
    int ntile = h >> 4, lc = h & 15, lane = hi * 16 + lc;
    WtB[((ntile * 8 + ks) * 64 + lane) * 8 + j2] = (short)f2bf_bits(s);
    if (k == 0) {
        float sb1 = 0.f, sb2 = 0.f;
        for (int j = 0; j < 128; ++j) {
            sb1 = fmaf(w_big[h * 128 + j], b_s1[j], sb1);
            sb2 = fmaf(w_big[h * 128 + j], b_s2[j], sb2);
        }
        bias[h] = b_big[h];
        bias[128 + h] = sb1;
        bias[256 + h] = sb2;
    }
}

// ---------------------------------------------------------------------------
// mm2: two independent 128x128x128 products + matvecs
// ---------------------------------------------------------------------------
__global__ __launch_bounds__(128) void mm2_k(
    const float* __restrict__ A0, const float* __restrict__ B0,
    const float* __restrict__ vin0, const float* __restrict__ vadd0,
    float* __restrict__ C0, float* __restrict__ v0,
    const float* __restrict__ A1, const float* __restrict__ B1,
    const float* __restrict__ vin1, const float* __restrict__ vadd1,
    float* __restrict__ C1, float* __restrict__ v1) {
    int blk = blockIdx.x, d = threadIdx.x, h = blk & 127;
    bool sec = blk >= 128;
    const float* A = sec ? A1 : A0;
    const float* B = sec ? B1 : B0;
    const float* vin = sec ? vin1 : vin0;
    const float* vadd = sec ? vadd1 : vadd0;
    float* C = sec ? C1 : C0;
    float* v = sec ? v1 : v0;
    __shared__ float rowv[128];
    __shared__ float red[128];
    rowv[d] = A[h * 128 + d];
    __syncthreads();
    float s = 0.f;
#pragma unroll 4
    for (int j = 0; j < 128; ++j) s = fmaf(rowv[j], B[j * 128 + d], s);
    C[h * 128 + d] = s;
    red[d] = rowv[d] * vin[d];
    __syncthreads();
    for (int off = 64; off > 0; off >>= 1) {
        if (d < off) red[d] += red[d + off];
        __syncthreads();
    }
    if (d == 0) v[h] = red[0] + (vadd ? vadd[h] : 0.f);
}

// ---------------------------------------------------------------------------
// finalize1: from pp1 stats + precomputed Wq/c1, emit WtB2 frags + bias2.
// ---------------------------------------------------------------------------
__global__ __launch_bounds__(128) void finalize1_k(
    const float* __restrict__ pp, const float* __restrict__ Wq_r,
    const float* __restrict__ Wq_p, const float* __restrict__ c1_r,
    const float* __restrict__ c1_p, const float* __restrict__ b_ma1,
    const float* __restrict__ g, const float* __restrict__ beta, float Nf,
    short* __restrict__ WtB, float* __restrict__ bias) {
    int k = blockIdx.x, h = threadIdx.x, kk = k & 127;
    const float* Wq = (k < 128) ? Wq_r : Wq_p;
    float ssum = 0.f, ssq = 0.f;
#pragma unroll 8
    for (int j = 0; j < 64; ++j) {
        ssum += pp[j * 256 + kk];
        ssq += pp[j * 256 + 128 + kk];
    }
    float mean = ssum / Nf;
    float var = ssq / Nf - mean * mean;
    float sv = g[kk] * rsqrtf(var + BN_EPS);
    float v = Wq[h * 128 + kk] * sv;
    int ks = k >> 5, hi = (k >> 3) & 3, j2 = k & 7;
    int ntile = h >> 4, lc = h & 15, lane = hi * 16 + lc;
    WtB[((ntile * 8 + ks) * 64 + lane) * 8 + j2] = (short)f2bf_bits(v);
    if (kk == 0) {
        __shared__ float t1[128];
        float sh = 0.f, qh = 0.f;
#pragma unroll 8
        for (int j = 0; j < 64; ++j) {
            sh += pp[j * 256 + h];
            qh += pp[j * 256 + 128 + h];
        }
        float mh = sh / Nf;
        float vh = qh / Nf - mh * mh;
        float svh = g[h] * rsqrtf(vh + BN_EPS);
        t1[h] = beta[h] - mh * svh;
        __syncthreads();
        float sb = 0.f;
#pragma unroll 4
        for (int d = 0; d < 128; ++d) sb = fmaf(Wq[h * 128 + d], t1[d], sb);
        if (k == 0) {
            bias[h] = b_ma1[h];
            bias[128 + h] = sb + c1_r[h];
        } else {
            bias[256 + h] = sb + c1_p[h];
        }
    }
}

// ---------------------------------------------------------------------------
// finalize2: from pp2 stats, emit WtBo frags (K=128) + b_out.
// ---------------------------------------------------------------------------
__global__ __launch_bounds__(128) void finalize2_k(
    const float* __restrict__ pp, const float* __restrict__ w_ma2,
    const float* __restrict__ b_ma2, const float* __restrict__ g,
    const float* __restrict__ beta, float Nf, short* __restrict__ WtBo,
    float* __restrict__ b_out) {
    int k = blockIdx.x, h = threadIdx.x;
    float ssum = 0.f, ssq = 0.f;
#pragma unroll 8
    for (int j = 0; j < 64; ++j) {
        ssum += pp[j * 256 + k];
        ssq += pp[j * 256 + 128 + k];
    }
    float mean = ssum / Nf;
    float var = ssq / Nf - mean * mean;
    float sv = g[k] * rsqrtf(var + BN_EPS);
    float v = w_ma2[h * 128 + k] * sv;
    int ks = k >> 5, hi = (k >> 3) & 3, j2 = k & 7;
    int ntile = h >> 4, lc = h & 15, lane = hi * 16 + lc;
    WtBo[((ntile * 4 + ks) * 64 + lane) * 8 + j2] = (short)f2bf_bits(v);
    if (k == 0) {
        __shared__ float t2[128];
        float sh = 0.f, qh = 0.f;
#pragma unroll 8
        for (int j = 0; j < 64; ++j) {
            sh += pp[j * 256 + h];
            qh += pp[j * 256 + 128 + h];
        }
        float mh = sh / Nf;
        float vh = qh / Nf - mh * mh;
        float svh = g[h] * rsqrtf(vh + BN_EPS);
        t2[h] = beta[h] - mh * svh;
        __syncthreads();
        float sb = 0.f;
#pragma unroll 4
        for (int d = 0; d < 128; ++d) sb = fmaf(w_ma2[h * 128 + d], t2[d], sb);
        b_out[h] = sb + b_ma2[h];
    }
}

// ---------------------------------------------------------------------------
// dense MFMA GEMM (GEMM5): Out[n,0:128] = bf16(A[n,0:128]) @ W + bias
// In-place safe (A fully staged to LDS before stores).
// ---------------------------------------------------------------------------
__global__ __launch_bounds__(512, 4) void gemm_dense_mfma(
    const float* A, const short* __restrict__ WtB,
    const float* __restrict__ biasv, float* Out) {
    __shared__ alignas(16) short Asm[64][136];
    const int t = threadIdx.x, n0 = blockIdx.x * 64;
    const int lane = t & 63, w = t >> 6;
    const int lrow = lane & 15, lhi = lane >> 4;

    {
        int row = t >> 3, g8 = t & 7;
        const float* p = A + (size_t)(n0 + row) * 128 + g8 * 16;
        u32* aw = (u32*)&Asm[0][0];
        int wb = row * 68 + g8 * 8;
#pragma unroll
        for (int c = 0; c < 2; ++c) {
            float4 a = *(const float4*)(p + c * 8);
            float4 b2 = *(const float4*)(p + c * 8 + 4);
            u32 pk0 = f2bf_bits(a.x) | (f2bf_bits(a.y) << 16);
            u32 pk1 = f2bf_bits(a.z) | (f2bf_bits(a.w) << 16);
            u32 pk2 = f2bf_bits(b2.x) | (f2bf_bits(b2.y) << 16);
            u32 pk3 = f2bf_bits(b2.z) | (f2bf_bits(b2.w) << 16);
            *(uint4*)&aw[wb + c * 4] = make_uint4(pk0, pk1, pk2, pk3);
        }
    }
    short8 bfrag[4];
#pragma unroll
    for (int ks = 0; ks < 4; ++ks)
        bfrag[ks] = *(const short8*)(WtB + (size_t)((w * 4 + ks) * 64 + lane) * 8);
    __syncthreads();

    f32x4 acc[4];
#pragma unroll
    for (int rt = 0; rt < 4; ++rt) acc[rt] = (f32x4){0.f, 0.f, 0.f, 0.f};
#pragma unroll
    for (int rt = 0; rt < 4; ++rt)
#pragma unroll
        for (int ks = 0; ks < 4; ++ks) {
            short8 af = *(const short8*)&Asm[rt * 16 + lrow][ks * 32 + lhi * 8];
            acc[rt] = MFMA16(af, bfrag[ks], acc[rt]);
        }
    int col = w * 16 + lrow;
    float bb = biasv[col];
#pragma unroll
    for (int rt = 0; rt < 4; ++rt)
#pragma unroll
        for (int i = 0; i < 4; ++i) {
            int row = rt * 16 + lhi * 4 + i;
            Out[(size_t)(n0 + row) * 128 + col] = acc[rt][i] + bb;
        }
}

// ---------------------------------------------------------------------------
// MFMA gather GEMM v4 (R6 geometry + interleaved halves).
// node-major src [nsrc, B=8, 128] bf16. Block = 8 bins x 8 batches = 64 rows,
// 512 threads = 8 waves; wave w owns bin (blockIdx*8+w); lane: batch=lane>>3,
// ck=lane&7. The two halves' edge lists are INDEPENDENT -> interleave their
// loops (ga/gb accumulators) so two 2KB bursts are always in flight.
// Per-block BN partials -> part[blk][256]. PERM: un-permute to batch-major.
// ---------------------------------------------------------------------------
template <typename OT, bool PERM>
__global__ __launch_bounds__(512, 4) void gemm_gather_mfma(
    const __hip_bfloat16* __restrict__ src,
    const int* __restrict__ off1, const int* __restrict__ idx1,
    const int* __restrict__ off2, const int* __restrict__ idx2,
    const short* __restrict__ WtB, const float* __restrict__ biasv,
    OT* __restrict__ Out, int permN, float* __restrict__ part) {
    __shared__ alignas(16) short Asm[64][264];
    __shared__ float m1s[64], m2s[64];
    const int t = threadIdx.x;
    const int lane = t & 63;
    const int w = __builtin_amdgcn_readfirstlane(t >> 6);
    const int lrow = lane & 15, lhi = lane >> 4;
    const int bin0 = blockIdx.x * 8;

    // B fragments early (in flight during gather); wave w -> col-tile w
    short8 bfrag[8];
#pragma unroll
    for (int ks = 0; ks < 8; ++ks)
        bfrag[ks] = *(const short8*)(WtB + (size_t)((w * 8 + ks) * 64 + lane) * 8);

    // ---- gather: wave w -> bin rb; both halves interleaved ----
    {
        const int rb = bin0 + w;
        const int batch = lane >> 3, ck = lane & 7;
        const int arow = w * 8 + batch;
        const __hip_bfloat16* lsrc = src + batch * 128 + ck * 16;
        int ea = off1[rb];
        const int e1a = off1[rb + 1];
        int eb = off2[rb];
        const int e1b = off2[rb + 1];
        const int cnta = e1a - ea, cntb = e1b - eb;
        float ga[16], gb[16];
#pragma unroll
        for (int j = 0; j < 16; ++j) { ga[j] = 0.f; gb[j] = 0.f; }
        while (ea < e1a && eb < e1b) {
            int ia = idx1[ea++];
            int ib = idx2[eb++];
            acc16(lsrc + (size_t)ia * 1024, ga);
            acc16(lsrc + (size_t)ib * 1024, gb);
        }
        for (; ea + 2 <= e1a; ea += 2) {
            int i0 = idx1[ea], i1 = idx1[ea + 1];
            acc16(lsrc + (size_t)i0 * 1024, ga);
            acc16(lsrc + (size_t)i1 * 1024, ga);
        }
        if (ea < e1a) acc16(lsrc + (size_t)idx1[ea] * 1024, ga);
        for (; eb + 2 <= e1b; eb += 2) {
            int i0 = idx2[eb], i1 = idx2[eb + 1];
            acc16(lsrc + (size_t)i0 * 1024, gb);
            acc16(lsrc + (size_t)i1 * 1024, gb);
        }
        if (eb < e1b) acc16(lsrc + (size_t)idx2[eb] * 1024, gb);

        float sca = (cnta > 0) ? 1.f / (float)cnta : 0.f;
        float scb = (cntb > 0) ? 1.f / (float)cntb : 0.f;
        if (ck == 0) {
            m1s[arow] = (cnta > 0) ? 1.f : 0.f;
            m2s[arow] = (cntb > 0) ? 1.f : 0.f;
        }
        u32* aw = (u32*)&Asm[0][0];
        int wba = arow * 132 + ck * 8;
        u32 pk[8];
#pragma unroll
        for (int q = 0; q < 8; ++q)
            pk[q] = f2bf_bits(ga[q * 2] * sca) | (f2bf_bits(ga[q * 2 + 1] * sca) << 16);
        *(uint4*)&aw[wba] = make_uint4(pk[0], pk[1], pk[2], pk[3]);
        *(uint4*)&aw[wba + 4] = make_uint4(pk[4], pk[5], pk[6], pk[7]);
#pragma unroll
        for (int q = 0; q < 8; ++q)
            pk[q] = f2bf_bits(gb[q * 2] * scb) | (f2bf_bits(gb[q * 2 + 1] * scb) << 16);
        *(uint4*)&aw[wba + 64] = make_uint4(pk[0], pk[1], pk[2], pk[3]);
        *(uint4*)&aw[wba + 68] = make_uint4(pk[4], pk[5], pk[6], pk[7]);
    }
    __syncthreads();

    // ---- MFMA: 4 row-tiles x 8 k-steps; wave w -> col-tile w ----
    f32x4 acc[4];
#pragma unroll
    for (int rt = 0; rt < 4; ++rt) acc[rt] = (f32x4){0.f, 0.f, 0.f, 0.f};
#pragma unroll
    for (int rt = 0; rt < 4; ++rt)
#pragma unroll
        for (int ks = 0; ks < 8; ++ks) {
            short8 af = *(const short8*)&Asm[rt * 16 + lrow][ks * 32 + lhi * 8];
            acc[rt] = MFMA16(af, bfrag[ks], acc[rt]);
        }

    // ---- epilogue ----
    const int col = w * 16 + lrow;
    float bb = biasv[col], bm1 = biasv[128 + col], bm2 = biasv[256 + col];
    float ps = 0.f, pq = 0.f;
#pragma unroll
    for (int rt = 0; rt < 4; ++rt)
#pragma unroll
        for (int i = 0; i < 4; ++i) {
            int row = rt * 16 + lhi * 4 + i;
            float v = acc[rt][i] + bb + m1s[row] * bm1 + m2s[row] * bm2;
            v = fmaxf(v, 0.f);
            ps += v;
            pq += v * v;
            size_t orow = PERM ? ((size_t)(row & 7) * permN + (bin0 + (row >> 3)))
                               : (size_t)(blockIdx.x * 64 + row);
            storev(&Out[orow * 128 + col], v);
        }
    ps += __shfl_xor(ps, 16);
    ps += __shfl_xor(ps, 32);
    pq += __shfl_xor(pq, 16);
    pq += __shfl_xor(pq, 32);
    if (lhi == 0) {
        part[(size_t)blockIdx.x * 256 + col] = ps;
        part[(size_t)blockIdx.x * 256 + 128 + col] = pq;
    }
}

// ---------------------------------------------------------------------------
// launch
// ---------------------------------------------------------------------------
extern "C" void kernel_launch(void* const* d_in, const int* in_sizes, int n_in,
                              void* d_out, int out_size, void* d_ws, size_t ws_size,
                              hipStream_t stream) {
    const float* nodes = (const float*)d_in[0];
    const int* r2e = (const int*)d_in[1];
    const int* p2e = (const int*)d_in[2];
    const int* e2r = (const int*)d_in[3];
    const int* e2p = (const int*)d_in[4];
    const float* w_rct = (const float*)d_in[5];
    const float* b_rct = (const float*)d_in[6];
    const float* w_prd = (const float*)d_in[7];
    const float* b_prd = (const float*)d_in[8];
    const float* w_ra1 = (const float*)d_in[9];
    const float* b_ra1 = (const float*)d_in[10];
    const float* bn_r_g = (const float*)d_in[11];
    const float* bn_r_b = (const float*)d_in[12];
    const float* w_ra2 = (const float*)d_in[13];
    const float* b_ra2 = (const float*)d_in[14];
    const float* w_r2rct = (const float*)d_in[15];
    const float* b_r2rct = (const float*)d_in[16];
    const float* w_r2prd = (const float*)d_in[17];
    const float* b_r2prd = (const float*)d_in[18];
    const float* w_ma1 = (const float*)d_in[19];
    const float* b_ma1 = (const float*)d_in[20];
    const float* bn_m_g = (const float*)d_in[21];
    const float* bn_m_b = (const float*)d_in[22];
    const float* w_ma2 = (const float*)d_in[23];
    const float* b_ma2 = (const float*)d_in[24];

    char* ws = (char*)d_ws;
    size_t off = 0;
    auto alloc = [&](size_t bytes) -> char* {
        off = (off + 255) & ~(size_t)255;
        char* p = ws + off;
        off += bytes;
        return p;
    };

    const size_t H1B = (size_t)NR * NB * 128 * 2;  // 102.4 MB node-major [R,B,128]
    __hip_bfloat16* h1 = (__hip_bfloat16*)alloc(H1B);

    char* cntcur = alloc((size_t)8 * (NR + NR + NM + NM));
    int* cnt_r = (int*)cntcur;
    int* cnt_p = cnt_r + NR;
    int* cnt_er = cnt_p + NR;
    int* cnt_ep = cnt_er + NM;
    int* cur_r = cnt_ep + NM;
    int* cur_p = cur_r + NR;
    int* cur_er = cur_p + NR;
    int* cur_ep = cur_er + NM;
    int* off_r = (int*)alloc((NR + 1) * 4);
    int* off_p = (int*)alloc((NR + 1) * 4);
    int* off_er = (int*)alloc((NM + 1) * 4);
    int* off_ep = (int*)alloc((NM + 1) * 4);
    int* idx_r = (int*)alloc(NE * 4);
    int* idx_p = (int*)alloc(NE * 4);
    int* idx_er = (int*)alloc(NE * 4);
    int* idx_ep = (int*)alloc(NE * 4);

    float* bias1 = (float*)alloc(3 * 128 * 4);
    float* bias2 = (float*)alloc(3 * 128 * 4);
    float* b_out = (float*)alloc(128 * 4);
    float* P_r = (float*)alloc(128 * 128 * 4);
    float* P_p = (float*)alloc(128 * 128 * 4);
    float* Wq_r = (float*)alloc(128 * 128 * 4);
    float* Wq_p = (float*)alloc(128 * 128 * 4);
    float* c1a_r = (float*)alloc(128 * 4);
    float* c1a_p = (float*)alloc(128 * 4);
    float* c1_r = (float*)alloc(128 * 4);
    float* c1_p = (float*)alloc(128 * 4);
    short* WtB1 = (short*)alloc(256 * 128 * 2);
    short* WtB2 = (short*)alloc(256 * 128 * 2);
    short* WtBo = (short*)alloc(128 * 128 * 2);
    const int NBLK1 = NR / 8;  // 6250
    const int NBLK2 = NM / 8;  // 2500
    float* part1 = (float*)alloc((size_t)NBLK1 * 256 * 4);  // 6.4 MB
    float* part2 = part1;                                   // sequential reuse
    float* pp1 = (float*)alloc(64 * 256 * 4);
    float* pp2 = pp1;  // sequential reuse
    (void)ws_size;

    // nb16 [M,B,128] bf16 (41 MB) lives in d_out; later overwritten by h2
    __hip_bfloat16* nb16 = (__hip_bfloat16*)d_out;
    float* h2 = (float*)d_out;

    hipMemsetAsync(cntcur, 0, (size_t)8 * (NR + NR + NM + NM), stream);

    // ---- CSR build (fused) ----
    const int EB = (NE + 255) / 256;
    hist4_k<<<dim3(EB, 4), 256, 0, stream>>>(r2e, p2e, e2r, e2p,
                                             cnt_r, cnt_p, cnt_er, cnt_ep);
    scan4_k<<<4, 1024, 0, stream>>>(cnt_r, off_r, NR, cnt_p, off_p, NR,
                                    cnt_er, off_er, NM, cnt_ep, off_ep, NM);
    fill4_k<<<dim3(EB, 4), 256, 0, stream>>>(r2e, p2e, e2r, e2p,
                                             off_r, off_p, off_er, off_ep,
                                             cur_r, cur_p, cur_er, cur_ep,
                                             idx_r, idx_p, idx_er, idx_ep);

    // ---- cast nodes -> node-major bf16 ----
    cast_nodes_k<<<(NB * NM * 128 / 8) / 256, 256, 0, stream>>>(nodes, nb16);

    // ---- stage-1 weights (direct to fragments) + stat-independent products ----
    prep1_frag_k<<<256, 128, 0, stream>>>(w_rct, w_prd, w_ra1, b_rct, b_prd, b_ra1,
                                          WtB1, bias1);
    mm2_k<<<256, 128, 0, stream>>>(w_ma1, w_r2rct, b_r2rct, nullptr, P_r, c1a_r,
                                   w_ma1, w_r2prd, b_r2prd, nullptr, P_p, c1a_p);
    mm2_k<<<256, 128, 0, stream>>>(P_r, w_ra2, b_ra2, c1a_r, Wq_r, c1_r,
                                   P_p, w_ra2, b_ra2, c1a_p, Wq_p, c1_p);

    // ---- GEMM2 (gather): h1 = relu(gather(nb16)@Wt1 + biases) + BN1 partials ----
    gemm_gather_mfma<__hip_bfloat16, false><<<NBLK1, 512, 0, stream>>>(
        nb16, off_r, idx_r, off_p, idx_p, WtB1, bias1, h1, 0, part1);
    reduce_part_k<<<64, 256, 0, stream>>>(part1, NBLK1, (NBLK1 + 63) / 64, pp1);
    finalize1_k<<<256, 128, 0, stream>>>(pp1, Wq_r, Wq_p, c1_r, c1_p, b_ma1,
                                         bn_r_g, bn_r_b, (float)((size_t)NB * NR),
                                         WtB2, bias2);

    // ---- GEMM4 (gather): h2[b,m,:] = relu(gather(h1)@Wt2 + biases) -> d_out ----
    gemm_gather_mfma<float, true><<<NBLK2, 512, 0, stream>>>(
        h1, off_er, idx_er, off_ep, idx_ep, WtB2, bias2, h2, NM, part2);
    reduce_part_k<<<64, 256, 0, stream>>>(part2, NBLK2, (NBLK2 + 63) / 64, pp2);
    finalize2_k<<<128, 128, 0, stream>>>(pp2, w_ma2, b_ma2, bn_m_g, bn_m_b,
                                         (float)((size_t)NB * NM), WtBo, b_out);

    // ---- GEMM5 (MFMA) in-place on d_out ----
    gemm_dense_mfma<<<(NB * NM) / 64, 512, 0, stream>>>(h2, WtBo, b_out, (float*)d_out);
}